// Round 1
// baseline (1776.431 us; speedup 1.0000x reference)
//
#include <hip/hip_runtime.h>
#include <hip/hip_bf16.h>
#include <cstdint>
#include <cstddef>

static constexpr int FD = 128;   // feature dim
static constexpr int NG = 16;    // graphs per batch
static constexpr int NL = 3;     // layers

// ---------------- CSR build ----------------
__global__ void k_count_deg(const int* __restrict__ edges, int* __restrict__ deg, int E) {
  int e = blockIdx.x * blockDim.x + threadIdx.x;
  if (e < E) atomicAdd(&deg[edges[E + e]], 1);
}

// single-block exclusive scan (Hillis-Steele per 1024-chunk with running carry)
__global__ void k_scan(const int* __restrict__ deg, int* __restrict__ off,
                       int* __restrict__ wptr, int n) {
  __shared__ int buf[1024];
  __shared__ int carry_s;
  if (threadIdx.x == 0) carry_s = 0;
  __syncthreads();
  for (int base = 0; base < n; base += 1024) {
    int i = base + (int)threadIdx.x;
    int v = (i < n) ? deg[i] : 0;
    int x = v;
    buf[threadIdx.x] = x;
    __syncthreads();
    #pragma unroll
    for (int s = 1; s < 1024; s <<= 1) {
      int t = (threadIdx.x >= (unsigned)s) ? buf[threadIdx.x - s] : 0;
      __syncthreads();
      x += t;
      buf[threadIdx.x] = x;
      __syncthreads();
    }
    int c = carry_s;                       // all threads read old carry
    if (i < n) { int ex = c + x - v; off[i] = ex; wptr[i] = ex; }
    __syncthreads();
    if (threadIdx.x == 1023) carry_s = c + buf[1023];
    __syncthreads();
  }
}

__global__ void k_fill_csr(const int* __restrict__ edges, int* __restrict__ wptr,
                           int* __restrict__ csr, int E) {
  int e = blockIdx.x * blockDim.x + threadIdx.x;
  if (e < E) {
    int s = edges[e];          // src
    int d = edges[E + e];      // dst
    int pos = atomicAdd(&wptr[d], 1);
    csr[pos] = s;
  }
}

// ---------------- neighbor mean (one block of 128 threads per dst node) ----------------
__global__ void k_agg_mean(const float* __restrict__ x, const int* __restrict__ csr,
                           const int* __restrict__ off, const int* __restrict__ deg,
                           float* __restrict__ mean) {
  int node = blockIdx.x;
  int t = threadIdx.x;
  int o = off[node];
  int d = deg[node];
  float acc = 0.f;
  for (int k = 0; k < d; ++k) {
    int s = csr[o + k];                       // wave-uniform broadcast load
    acc += x[(size_t)s * FD + t];             // 512B coalesced row read
  }
  float inv = 1.f / fmaxf((float)d, 1.f);
  mean[(size_t)node * FD + t] = acc * inv;
}

// ---------------- fused y = relu(mean@Wl + x@Wr + b) ----------------
// block: 256 threads = 8 row-groups x 32 col-groups; tile 64 rows x 128 cols
// W chunk (32x128) staged in LDS (read once per block); A read direct from
// global (address uniform across the 32 col-lanes -> broadcast transaction).
__global__ __launch_bounds__(256) void k_gemm_relu(
    const float* __restrict__ Am, const float* __restrict__ Ax,
    const float* __restrict__ Wl, const float* __restrict__ Wr,
    const float* __restrict__ bias, float* __restrict__ out, int n)
{
  __shared__ float Ws[32][FD];
  int tid = (int)threadIdx.x;
  int tx = tid & 31;           // col group: cols tx*4 .. tx*4+3
  int ty = tid >> 5;           // row group: rows ty*8 .. ty*8+7
  int row0 = blockIdx.x * 64 + ty * 8;
  float acc[8][4];
  #pragma unroll
  for (int r = 0; r < 8; r++)
    #pragma unroll
    for (int c = 0; c < 4; c++) acc[r][c] = 0.f;

  #pragma unroll
  for (int half = 0; half < 2; half++) {
    const float* __restrict__ A = half ? Ax : Am;
    const float* __restrict__ W = half ? Wr : Wl;
    for (int kc = 0; kc < FD; kc += 32) {
      __syncthreads();
      #pragma unroll
      for (int q = 0; q < 4; q++) {        // stage 32x128 W chunk, coalesced float4
        int f = q * 256 + tid;
        int r = f >> 5;
        int c = (f & 31) * 4;
        *(float4*)&Ws[r][c] = *(const float4*)&W[(size_t)(kc + r) * FD + c];
      }
      __syncthreads();
      #pragma unroll
      for (int k4 = 0; k4 < 32; k4 += 4) {
        float4 a4[8];
        #pragma unroll
        for (int r = 0; r < 8; r++) {
          int row = row0 + r;
          int rr = row < n ? row : 0;
          a4[r] = *(const float4*)&A[(size_t)rr * FD + kc + k4];
        }
        #pragma unroll
        for (int kk = 0; kk < 4; kk++) {
          float4 w4 = *(const float4*)&Ws[k4 + kk][tx * 4];
          #pragma unroll
          for (int r = 0; r < 8; r++) {
            float a = (kk == 0) ? a4[r].x : (kk == 1) ? a4[r].y
                    : (kk == 2) ? a4[r].z : a4[r].w;
            acc[r][0] = fmaf(a, w4.x, acc[r][0]);
            acc[r][1] = fmaf(a, w4.y, acc[r][1]);
            acc[r][2] = fmaf(a, w4.z, acc[r][2]);
            acc[r][3] = fmaf(a, w4.w, acc[r][3]);
          }
        }
      }
    }
  }
  float4 b4 = *(const float4*)&bias[tx * 4];
  #pragma unroll
  for (int r = 0; r < 8; r++) {
    int row = row0 + r;
    if (row < n) {
      float4 o;
      o.x = fmaxf(acc[r][0] + b4.x, 0.f);
      o.y = fmaxf(acc[r][1] + b4.y, 0.f);
      o.z = fmaxf(acc[r][2] + b4.z, 0.f);
      o.w = fmaxf(acc[r][3] + b4.w, 0.f);
      *(float4*)&out[(size_t)row * FD + tx * 4] = o;
    }
  }
}

// ---------------- graph mean-pool (batch is sorted; register-accumulate per run) ----------------
__global__ void k_pool(const float* __restrict__ x, const int* __restrict__ batch,
                       float* __restrict__ pool, float* __restrict__ pcnt, int n) {
  __shared__ float acc[NG][FD];
  __shared__ float cnt[NG];
  int t = (int)threadIdx.x;   // 128
  #pragma unroll
  for (int g = 0; g < NG; g++) acc[g][t] = 0.f;
  if (t < NG) cnt[t] = 0.f;
  __syncthreads();
  int start = blockIdx.x * 512;
  int end = min(start + 512, n);
  if (start < end) {
    float racc = 0.f, rcnt = 0.f;
    int curg = batch[start];
    for (int i = start; i < end; i++) {
      int g = batch[i];                       // wave-uniform
      if (g != curg) {
        acc[curg][t] += racc;
        if (t == 0) cnt[curg] += rcnt;
        racc = 0.f; rcnt = 0.f; curg = g;
      }
      racc += x[(size_t)i * FD + t];
      rcnt += 1.f;
    }
    acc[curg][t] += racc;
    if (t == 0) cnt[curg] += rcnt;
  }
  __syncthreads();
  #pragma unroll
  for (int g = 0; g < NG; g++) atomicAdd(&pool[g * FD + t], acc[g][t]);
  if (t < NG) atomicAdd(&pcnt[t], cnt[t]);
}

// ---------------- head: out[g,o] = sum_d (pool[t][g][d]/cnt) * linW[t*128+d][o] + b[o] ----------------
__global__ void k_final(const float* __restrict__ pool, const float* __restrict__ pcnt,
                        const float* __restrict__ linW, const float* __restrict__ linb,
                        float* __restrict__ out) {
  int tid = (int)threadIdx.x;
  if (tid < NG * 2) {
    int g = tid >> 1, o = tid & 1;
    float s = linb[o];
    for (int t = 0; t < 2; t++) {
      float inv = 1.f / fmaxf(pcnt[t * NG + g], 1.f);
      for (int d = 0; d < FD; d++) {
        float h = pool[(t * NG + g) * FD + d] * inv;
        s = fmaf(h, linW[(t * FD + d) * 2 + o], s);
      }
    }
    out[g * 2 + o] = s;
  }
}

extern "C" void kernel_launch(void* const* d_in, const int* in_sizes, int n_in,
                              void* d_out, int out_size, void* d_ws, size_t ws_size,
                              hipStream_t stream) {
  const float* x_in[2] = {(const float*)d_in[0], (const float*)d_in[1]};
  const float* Wl   = (const float*)d_in[2];
  const float* bl   = (const float*)d_in[3];
  const float* Wr   = (const float*)d_in[4];
  const float* linW = (const float*)d_in[5];
  const float* linb = (const float*)d_in[6];
  const int* edges[2] = {(const int*)d_in[7], (const int*)d_in[8]};
  const int* batch[2] = {(const int*)d_in[9], (const int*)d_in[10]};

  const int N = in_sizes[0] / FD;    // 50000
  const int E = in_sizes[7] / 2;     // 800000

  // ---- workspace layout (512B aligned) ----
  char* p = (char*)d_ws;
  auto alloc = [&](size_t bytes) -> char* {
    char* r = p; p += (bytes + 511) & ~(size_t)511; return r;
  };
  int* deg[2];  deg[0]  = (int*)alloc((size_t)N * 4); deg[1]  = (int*)alloc((size_t)N * 4);
  float* pool  = (float*)alloc(2 * NG * FD * 4);
  float* pcnt  = (float*)alloc(2 * NG * 4);
  size_t zero_bytes = (size_t)(p - (char*)d_ws);       // deg+pool+pcnt need zeroing
  int* off[2];  off[0]  = (int*)alloc((size_t)N * 4); off[1]  = (int*)alloc((size_t)N * 4);
  int* wptr[2]; wptr[0] = (int*)alloc((size_t)N * 4); wptr[1] = (int*)alloc((size_t)N * 4);
  int* csr[2];  csr[0]  = (int*)alloc((size_t)E * 4); csr[1]  = (int*)alloc((size_t)E * 4);
  float* meanb = (float*)alloc((size_t)N * FD * 4);
  float* xbuf[2][2];
  for (int t = 0; t < 2; t++)
    for (int b = 0; b < 2; b++) xbuf[t][b] = (float*)alloc((size_t)N * FD * 4);
  if ((size_t)(p - (char*)d_ws) > ws_size) return;     // insufficient workspace

  hipMemsetAsync(d_ws, 0, zero_bytes, stream);

  int eb = (E + 255) / 256;
  for (int t = 0; t < 2; t++) k_count_deg<<<eb, 256, 0, stream>>>(edges[t], deg[t], E);
  for (int t = 0; t < 2; t++) k_scan<<<1, 1024, 0, stream>>>(deg[t], off[t], wptr[t], N);
  for (int t = 0; t < 2; t++) k_fill_csr<<<eb, 256, 0, stream>>>(edges[t], wptr[t], csr[t], E);

  int gblocks = (N + 63) / 64;
  const float* cur[2] = {x_in[0], x_in[1]};
  int pp = 0;
  for (int l = 0; l < NL; l++) {
    for (int t = 0; t < 2; t++) {
      int wi = l * 2 + t;
      float* nxt = xbuf[t][pp];
      k_agg_mean<<<N, FD, 0, stream>>>(cur[t], csr[t], off[t], deg[t], meanb);
      k_gemm_relu<<<gblocks, 256, 0, stream>>>(
          meanb, cur[t],
          Wl + (size_t)wi * FD * FD, Wr + (size_t)wi * FD * FD,
          bl + (size_t)wi * FD, nxt, N);
      cur[t] = nxt;
    }
    pp ^= 1;
  }

  int pblocks = (N + 511) / 512;
  for (int t = 0; t < 2; t++)
    k_pool<<<pblocks, FD, 0, stream>>>(cur[t], batch[t], pool + t * NG * FD, pcnt + t * NG, N);
  k_final<<<1, 64, 0, stream>>>(pool, pcnt, linW, linb, (float*)d_out);
}

// Round 2
// 1293.411 us; speedup vs baseline: 1.3734x; 1.3734x over previous
//
#include <hip/hip_runtime.h>
#include <hip/hip_bf16.h>
#include <cstdint>
#include <cstddef>

static constexpr int FD = 128;   // feature dim
static constexpr int NG = 16;    // graphs per batch
static constexpr int NL = 3;     // layers

// ---------------- CSR build ----------------
__global__ void k_count_deg(const int* __restrict__ edges, int* __restrict__ deg, int E) {
  int e = blockIdx.x * blockDim.x + threadIdx.x;
  if (e < E) atomicAdd(&deg[edges[E + e]], 1);
}

// single-block scan: wave shfl-scan, 4 elems/thread, few barriers
__global__ __launch_bounds__(1024) void k_scan(const int* __restrict__ deg,
                                               int* __restrict__ off,
                                               int* __restrict__ wptr, int n) {
  __shared__ int wsum[16];
  __shared__ int carry_s;
  int tid = (int)threadIdx.x;
  int lane = tid & 63;
  int wave = tid >> 6;
  if (tid == 0) carry_s = 0;
  __syncthreads();
  for (int base = 0; base < n; base += 4096) {
    int i0 = base + tid * 4;
    int v[4];
    int s = 0;
    #pragma unroll
    for (int j = 0; j < 4; j++) { v[j] = (i0 + j < n) ? deg[i0 + j] : 0; s += v[j]; }
    // inclusive wave scan of thread sums
    int sc = s;
    #pragma unroll
    for (int d = 1; d < 64; d <<= 1) {
      int t = __shfl_up(sc, d, 64);
      if (lane >= d) sc += t;
    }
    if (lane == 63) wsum[wave] = sc;
    __syncthreads();
    if (wave == 0 && lane < 16) {
      int ws = wsum[lane];
      int wsc = ws;
      #pragma unroll
      for (int d = 1; d < 16; d <<= 1) {
        int t = __shfl_up(wsc, d, 64);
        if (lane >= d) wsc += t;
      }
      wsum[lane] = wsc - ws;   // exclusive wave prefix
    }
    __syncthreads();
    int excl = carry_s + wsum[wave] + (sc - s);
    #pragma unroll
    for (int j = 0; j < 4; j++) {
      if (i0 + j < n) { off[i0 + j] = excl; wptr[i0 + j] = excl; }
      excl += v[j];
    }
    __syncthreads();
    if (tid == 1023) carry_s += wsum[15] + sc;   // chunk total
    __syncthreads();
  }
}

__global__ void k_fill_csr(const int* __restrict__ edges, int* __restrict__ wptr,
                           int* __restrict__ csr, int E) {
  int e = blockIdx.x * blockDim.x + threadIdx.x;
  if (e < E) {
    int s = edges[e];          // src
    int d = edges[E + e];      // dst
    int pos = atomicAdd(&wptr[d], 1);
    csr[pos] = s;
  }
}

// ---------------- neighbor mean: 8 nodes/block, float4, x4 unrolled gathers ----------------
__global__ __launch_bounds__(256) void k_agg_mean(
    const float* __restrict__ x, const int* __restrict__ csr,
    const int* __restrict__ off, const int* __restrict__ deg,
    float* __restrict__ mean, int n) {
  int node = blockIdx.x * 8 + ((int)threadIdx.x >> 5);
  if (node >= n) return;
  int c4 = ((int)threadIdx.x & 31) * 4;
  int o = off[node];
  int d = deg[node];
  float4 acc = make_float4(0.f, 0.f, 0.f, 0.f);
  int k = 0;
  for (; k + 4 <= d; k += 4) {
    int s0 = csr[o + k + 0];
    int s1 = csr[o + k + 1];
    int s2 = csr[o + k + 2];
    int s3 = csr[o + k + 3];
    float4 v0 = *(const float4*)&x[(size_t)s0 * FD + c4];
    float4 v1 = *(const float4*)&x[(size_t)s1 * FD + c4];
    float4 v2 = *(const float4*)&x[(size_t)s2 * FD + c4];
    float4 v3 = *(const float4*)&x[(size_t)s3 * FD + c4];
    acc.x += (v0.x + v1.x) + (v2.x + v3.x);
    acc.y += (v0.y + v1.y) + (v2.y + v3.y);
    acc.z += (v0.z + v1.z) + (v2.z + v3.z);
    acc.w += (v0.w + v1.w) + (v2.w + v3.w);
  }
  for (; k < d; k++) {
    int s = csr[o + k];
    float4 v = *(const float4*)&x[(size_t)s * FD + c4];
    acc.x += v.x; acc.y += v.y; acc.z += v.z; acc.w += v.w;
  }
  float inv = 1.f / fmaxf((float)d, 1.f);
  float4 o4 = make_float4(acc.x * inv, acc.y * inv, acc.z * inv, acc.w * inv);
  *(float4*)&mean[(size_t)node * FD + c4] = o4;
}

// ---------------- fused y = relu(mean@Wl + x@Wr + b) ----------------
// block: 256 threads = 8 row-groups x 32 col-groups; tile 64 rows x 128 cols
__global__ __launch_bounds__(256) void k_gemm_relu(
    const float* __restrict__ Am, const float* __restrict__ Ax,
    const float* __restrict__ Wl, const float* __restrict__ Wr,
    const float* __restrict__ bias, float* __restrict__ out, int n)
{
  __shared__ float Ws[32][FD];
  int tid = (int)threadIdx.x;
  int tx = tid & 31;           // col group: cols tx*4 .. tx*4+3
  int ty = tid >> 5;           // row group: rows ty*8 .. ty*8+7
  int row0 = blockIdx.x * 64 + ty * 8;
  float acc[8][4];
  #pragma unroll
  for (int r = 0; r < 8; r++)
    #pragma unroll
    for (int c = 0; c < 4; c++) acc[r][c] = 0.f;

  #pragma unroll
  for (int half = 0; half < 2; half++) {
    const float* __restrict__ A = half ? Ax : Am;
    const float* __restrict__ W = half ? Wr : Wl;
    for (int kc = 0; kc < FD; kc += 32) {
      __syncthreads();
      #pragma unroll
      for (int q = 0; q < 4; q++) {        // stage 32x128 W chunk, coalesced float4
        int f = q * 256 + tid;
        int r = f >> 5;
        int c = (f & 31) * 4;
        *(float4*)&Ws[r][c] = *(const float4*)&W[(size_t)(kc + r) * FD + c];
      }
      __syncthreads();
      #pragma unroll
      for (int k4 = 0; k4 < 32; k4 += 4) {
        float4 a4[8];
        #pragma unroll
        for (int r = 0; r < 8; r++) {
          int row = row0 + r;
          int rr = row < n ? row : 0;
          a4[r] = *(const float4*)&A[(size_t)rr * FD + kc + k4];
        }
        #pragma unroll
        for (int kk = 0; kk < 4; kk++) {
          float4 w4 = *(const float4*)&Ws[k4 + kk][tx * 4];
          #pragma unroll
          for (int r = 0; r < 8; r++) {
            float a = (kk == 0) ? a4[r].x : (kk == 1) ? a4[r].y
                    : (kk == 2) ? a4[r].z : a4[r].w;
            acc[r][0] = fmaf(a, w4.x, acc[r][0]);
            acc[r][1] = fmaf(a, w4.y, acc[r][1]);
            acc[r][2] = fmaf(a, w4.z, acc[r][2]);
            acc[r][3] = fmaf(a, w4.w, acc[r][3]);
          }
        }
      }
    }
  }
  float4 b4 = *(const float4*)&bias[tx * 4];
  #pragma unroll
  for (int r = 0; r < 8; r++) {
    int row = row0 + r;
    if (row < n) {
      float4 o;
      o.x = fmaxf(acc[r][0] + b4.x, 0.f);
      o.y = fmaxf(acc[r][1] + b4.y, 0.f);
      o.z = fmaxf(acc[r][2] + b4.z, 0.f);
      o.w = fmaxf(acc[r][3] + b4.w, 0.f);
      *(float4*)&out[(size_t)row * FD + tx * 4] = o;
    }
  }
}

// ---------------- graph mean-pool: 128 rows/block, float4, run-flush atomics ----------------
__global__ __launch_bounds__(256) void k_pool(
    const float* __restrict__ x, const int* __restrict__ batch,
    float* __restrict__ pool, float* __restrict__ pcnt, int n) {
  int tid = (int)threadIdx.x;
  int c4 = (tid & 31) * 4;
  int rs = tid >> 5;
  int start = blockIdx.x * 128;
  int end = min(start + 128, n);
  if (start >= end) return;

  float4 acc = make_float4(0.f, 0.f, 0.f, 0.f);
  float cnt = 0.f;
  auto flush = [&](int g) {
    atomicAdd(&pool[g * FD + c4 + 0], acc.x);
    atomicAdd(&pool[g * FD + c4 + 1], acc.y);
    atomicAdd(&pool[g * FD + c4 + 2], acc.z);
    atomicAdd(&pool[g * FD + c4 + 3], acc.w);
    if ((tid & 31) == 0) atomicAdd(&pcnt[g], cnt);
  };

  int gfirst = batch[start];
  int glast = batch[end - 1];
  if (gfirst == glast) {
    // fast path: whole chunk is one graph — branch-free accumulate
    for (int i = start + rs; i < end; i += 8) {
      float4 v = *(const float4*)&x[(size_t)i * FD + c4];
      acc.x += v.x; acc.y += v.y; acc.z += v.z; acc.w += v.w;
      cnt += 1.f;
    }
    flush(gfirst);
  } else {
    int curg = -1;
    for (int i = start + rs; i < end; i += 8) {
      int g = batch[i];
      if (g != curg) {
        if (curg >= 0) flush(curg);
        curg = g;
        acc = make_float4(0.f, 0.f, 0.f, 0.f);
        cnt = 0.f;
      }
      float4 v = *(const float4*)&x[(size_t)i * FD + c4];
      acc.x += v.x; acc.y += v.y; acc.z += v.z; acc.w += v.w;
      cnt += 1.f;
    }
    if (curg >= 0) flush(curg);
  }
}

// ---------------- head ----------------
__global__ void k_final(const float* __restrict__ pool, const float* __restrict__ pcnt,
                        const float* __restrict__ linW, const float* __restrict__ linb,
                        float* __restrict__ out) {
  int tid = (int)threadIdx.x;
  if (tid < NG * 2) {
    int g = tid >> 1, o = tid & 1;
    float s = linb[o];
    for (int t = 0; t < 2; t++) {
      float inv = 1.f / fmaxf(pcnt[t * NG + g], 1.f);
      for (int d = 0; d < FD; d++) {
        float h = pool[(t * NG + g) * FD + d] * inv;
        s = fmaf(h, linW[(t * FD + d) * 2 + o], s);
      }
    }
    out[g * 2 + o] = s;
  }
}

extern "C" void kernel_launch(void* const* d_in, const int* in_sizes, int n_in,
                              void* d_out, int out_size, void* d_ws, size_t ws_size,
                              hipStream_t stream) {
  const float* x_in[2] = {(const float*)d_in[0], (const float*)d_in[1]};
  const float* Wl   = (const float*)d_in[2];
  const float* bl   = (const float*)d_in[3];
  const float* Wr   = (const float*)d_in[4];
  const float* linW = (const float*)d_in[5];
  const float* linb = (const float*)d_in[6];
  const int* edges[2] = {(const int*)d_in[7], (const int*)d_in[8]};
  const int* batch[2] = {(const int*)d_in[9], (const int*)d_in[10]};

  const int N = in_sizes[0] / FD;    // 50000
  const int E = in_sizes[7] / 2;     // 800000

  // ---- workspace layout (512B aligned) ----
  char* p = (char*)d_ws;
  auto alloc = [&](size_t bytes) -> char* {
    char* r = p; p += (bytes + 511) & ~(size_t)511; return r;
  };
  int* deg[2];  deg[0]  = (int*)alloc((size_t)N * 4); deg[1]  = (int*)alloc((size_t)N * 4);
  float* pool  = (float*)alloc(2 * NG * FD * 4);
  float* pcnt  = (float*)alloc(2 * NG * 4);
  size_t zero_bytes = (size_t)(p - (char*)d_ws);       // deg+pool+pcnt need zeroing
  int* off[2];  off[0]  = (int*)alloc((size_t)N * 4); off[1]  = (int*)alloc((size_t)N * 4);
  int* wptr[2]; wptr[0] = (int*)alloc((size_t)N * 4); wptr[1] = (int*)alloc((size_t)N * 4);
  int* csr[2];  csr[0]  = (int*)alloc((size_t)E * 4); csr[1]  = (int*)alloc((size_t)E * 4);
  float* meanb = (float*)alloc((size_t)N * FD * 4);
  float* xbuf[2][2];
  for (int t = 0; t < 2; t++)
    for (int b = 0; b < 2; b++) xbuf[t][b] = (float*)alloc((size_t)N * FD * 4);
  if ((size_t)(p - (char*)d_ws) > ws_size) return;     // insufficient workspace

  hipMemsetAsync(d_ws, 0, zero_bytes, stream);

  int eb = (E + 255) / 256;
  for (int t = 0; t < 2; t++) k_count_deg<<<eb, 256, 0, stream>>>(edges[t], deg[t], E);
  for (int t = 0; t < 2; t++) k_scan<<<1, 1024, 0, stream>>>(deg[t], off[t], wptr[t], N);
  for (int t = 0; t < 2; t++) k_fill_csr<<<eb, 256, 0, stream>>>(edges[t], wptr[t], csr[t], E);

  int gblocks = (N + 63) / 64;
  int ablocks = (N + 7) / 8;
  const float* cur[2] = {x_in[0], x_in[1]};
  int pp = 0;
  for (int l = 0; l < NL; l++) {
    for (int t = 0; t < 2; t++) {
      int wi = l * 2 + t;
      float* nxt = xbuf[t][pp];
      k_agg_mean<<<ablocks, 256, 0, stream>>>(cur[t], csr[t], off[t], deg[t], meanb, N);
      k_gemm_relu<<<gblocks, 256, 0, stream>>>(
          meanb, cur[t],
          Wl + (size_t)wi * FD * FD, Wr + (size_t)wi * FD * FD,
          bl + (size_t)wi * FD, nxt, N);
      cur[t] = nxt;
    }
    pp ^= 1;
  }

  int pblocks = (N + 127) / 128;
  for (int t = 0; t < 2; t++)
    k_pool<<<pblocks, 256, 0, stream>>>(cur[t], batch[t], pool + t * NG * FD, pcnt + t * NG, N);
  k_final<<<1, 64, 0, stream>>>(pool, pcnt, linW, linb, (float*)d_out);
}